// Round 8
// baseline (3116.704 us; speedup 1.0000x reference)
//
#include <hip/hip_runtime.h>
#include <math.h>

// Sinkhorn loss, B=16 batches of N=1536 1D points, fp32.
// 18 softmin rounds, one kernel launch each (cooperative launch is rejected
// by this harness -- R3/R7 both failed with d_out untouched).
// R8 vs R2: 1536 blocks (6 blocks/CU = 6 waves/SIMD, 2x TLP) and 4-deep
// explicit LDS load batches in both LSE passes (4 outstanding ds_read_b128
// to hide ~100cyc LDS latency). R=4 rows/thread, VGPR kept low.
//
// ws layout (floats): eps0[16] | F0[B*N] | F1[B*N] | G0[B*N] | G1[B*N]

static constexpr int   BN    = 16;
static constexpr int   NP    = 1536;
static constexpr float BLUR2 = 0.0025f;                 // blur^2
static constexpr float L2E   = 1.4426950408889634f;     // log2(e)
static constexpr float LN2   = 0.6931471805599453f;     // ln(2)
static constexpr float HLOG  = -7.33693691f;            // -log(1536)

#if defined(__has_builtin)
#if __has_builtin(__builtin_amdgcn_exp2f)
#define EXP2F(x) __builtin_amdgcn_exp2f(x)
#else
#define EXP2F(x) exp2f(x)
#endif
#else
#define EXP2F(x) exp2f(x)
#endif

__global__ __launch_bounds__(256) void sk_setup(const float* __restrict__ x,
                                                const float* __restrict__ y,
                                                float* __restrict__ eps0) {
    const int b = blockIdx.x;
    const int t = threadIdx.x;
    float mn = INFINITY, mx = -INFINITY;
    for (int j = t; j < NP; j += 256) {
        float xv = x[b * NP + j], yv = y[b * NP + j];
        mn = fminf(mn, fminf(xv, yv));
        mx = fmaxf(mx, fmaxf(xv, yv));
    }
    for (int o = 1; o < 64; o <<= 1) {
        mn = fminf(mn, __shfl_xor(mn, o));
        mx = fmaxf(mx, __shfl_xor(mx, o));
    }
    __shared__ float smn[4], smx[4];
    const int w = t >> 6;
    if ((t & 63) == 0) { smn[w] = mn; smx[w] = mx; }
    __syncthreads();
    if (t == 0) {
        mn = fminf(fminf(smn[0], smn[1]), fminf(smn[2], smn[3]));
        mx = fmaxf(fmaxf(smx[0], smx[1]), fmaxf(smx[2], smx[3]));
        float d = mx - mn;
        eps0[b] = d * d;
    }
}

// grid = 1536 blocks: batch (16) x {dir f: 48, dir g: 48} row-blocks of 32.
// Block = 8 groups x 32 lanes; group owns 4 rows, lanes split the columns.
__global__ __launch_bounds__(256, 6) void sk_round(const float* __restrict__ x,
                                                   const float* __restrict__ y,
                                                   float* __restrict__ ws,
                                                   float* __restrict__ out,
                                                   int round) {
    __shared__ __align__(16) float2 cu[NP];   // (col_coord_j, U_j) ; 12 KB
    __shared__ float wsum[4];

    const int blk    = blockIdx.x;       // 0..1535
    const int batch  = blk / 96;
    const int rb     = blk % 96;
    const int dir    = (rb < 48) ? 0 : 1;
    const int rowblk = rb - dir * 48;    // 0..47

    float* F0 = ws + 16;
    float* F1 = F0 + BN * NP;
    float* G0 = F1 + BN * NP;
    float* G1 = G0 + BN * NP;
    const int ri = (round + 1) & 1;      // read parity
    const int wi = round & 1;            // write parity
    float* Fr = ri ? F1 : F0;  float* Fw = wi ? F1 : F0;
    float* Gr = ri ? G1 : G0;  float* Gw = wi ? G1 : G0;

    const float* colc; const float* rowc; const float* hsrc;
    float* obuf; const float* oldb;
    if (dir == 0) { // ft rows: rows over x_i, cols over y_j, h from g
        colc = y + batch * NP; rowc = x + batch * NP;
        hsrc = Gr + batch * NP; obuf = Fw + batch * NP; oldb = Fr + batch * NP;
    } else {        // gt rows: rows over y_i, cols over x_j, h from f
        colc = x + batch * NP; rowc = y + batch * NP;
        hsrc = Fr + batch * NP; obuf = Gw + batch * NP; oldb = Gr + batch * NP;
    }

    // eps_k = max(blur^2, eps0 * 0.25^max(k-1,0)); round 1..16 = step k-1
    const float e0 = ws[batch];
    float eps;
    if (round == 0)       eps = fmaxf(BLUR2, e0);
    else if (round >= 17) eps = BLUR2;
    else {
        int mk = round - 2; if (mk < 0) mk = 0;
        eps = fmaxf(BLUR2, e0 / (float)(1u << (2 * mk)));   // exact pow2 scale
    }
    const float ieps = 1.0f / eps;
    const float cL   = 0.5f * ieps * L2E;

    // Stage column table: U_j = L2E*h_j - cL*c_j^2, h_j = HLOG + g_j/eps
    const int t = threadIdx.x;
    for (int j = t; j < NP; j += 256) {
        float cj = colc[j];
        float hj = (round == 0) ? HLOG : fmaf(hsrc[j], ieps, HLOG);
        cu[j] = make_float2(cj, fmaf(L2E, hj, -cL * cj * cj));
    }
    __syncthreads();

    const int l  = t & 31;       // lane within group: splits columns
    const int g  = t >> 5;       // group 0..7: owns 4 rows
    const int i0 = rowblk * 32 + g * 4;

    float S[4], Kc[4];
    #pragma unroll
    for (int r = 0; r < 4; ++r) {
        float xi = rowc[i0 + r];
        S[r]  = 2.0f * cL * xi;          // exponent = U_j + S*col_j + Kc
        Kc[r] = -cL * xi * xi;
    }

    const float4* p = (const float4*)cu;   // 768 entries, 2 cols each
    // 24 strided iterations per lane, processed as 6 batches of 4 loads.

    // pass 1: max
    float m[4];
    #pragma unroll
    for (int r = 0; r < 4; ++r) m[r] = -INFINITY;
    #pragma unroll
    for (int qb = 0; qb < 6; ++qb) {
        const int q0 = l + qb * 128;               // qb*4 strides of 32
        float4 a0 = p[q0];
        float4 a1 = p[q0 + 32];
        float4 a2 = p[q0 + 64];
        float4 a3 = p[q0 + 96];
        #pragma unroll
        for (int r = 0; r < 4; ++r) {
            m[r] = fmaxf(fmaxf(fmaf(S[r], a0.x, a0.y), fmaf(S[r], a0.z, a0.w)), m[r]);
            m[r] = fmaxf(fmaxf(fmaf(S[r], a1.x, a1.y), fmaf(S[r], a1.z, a1.w)), m[r]);
            m[r] = fmaxf(fmaxf(fmaf(S[r], a2.x, a2.y), fmaf(S[r], a2.z, a2.w)), m[r]);
            m[r] = fmaxf(fmaxf(fmaf(S[r], a3.x, a3.y), fmaf(S[r], a3.z, a3.w)), m[r]);
        }
    }
    #pragma unroll
    for (int r = 0; r < 4; ++r) {
        m[r] = fmaxf(m[r], __shfl_xor(m[r], 1));
        m[r] = fmaxf(m[r], __shfl_xor(m[r], 2));
        m[r] = fmaxf(m[r], __shfl_xor(m[r], 4));
        m[r] = fmaxf(m[r], __shfl_xor(m[r], 8));
        m[r] = fmaxf(m[r], __shfl_xor(m[r], 16));
    }

    // pass 2: sum of 2^(v-m)
    float s[4];
    #pragma unroll
    for (int r = 0; r < 4; ++r) s[r] = 0.0f;
    #pragma unroll
    for (int qb = 0; qb < 6; ++qb) {
        const int q0 = l + qb * 128;
        float4 a0 = p[q0];
        float4 a1 = p[q0 + 32];
        float4 a2 = p[q0 + 64];
        float4 a3 = p[q0 + 96];
        #pragma unroll
        for (int r = 0; r < 4; ++r) {
            s[r] += EXP2F(fmaf(S[r], a0.x, a0.y) - m[r]);
            s[r] += EXP2F(fmaf(S[r], a0.z, a0.w) - m[r]);
            s[r] += EXP2F(fmaf(S[r], a1.x, a1.y) - m[r]);
            s[r] += EXP2F(fmaf(S[r], a1.z, a1.w) - m[r]);
            s[r] += EXP2F(fmaf(S[r], a2.x, a2.y) - m[r]);
            s[r] += EXP2F(fmaf(S[r], a2.z, a2.w) - m[r]);
            s[r] += EXP2F(fmaf(S[r], a3.x, a3.y) - m[r]);
            s[r] += EXP2F(fmaf(S[r], a3.z, a3.w) - m[r]);
        }
    }
    #pragma unroll
    for (int r = 0; r < 4; ++r) {
        s[r] += __shfl_xor(s[r], 1);
        s[r] += __shfl_xor(s[r], 2);
        s[r] += __shfl_xor(s[r], 4);
        s[r] += __shfl_xor(s[r], 8);
        s[r] += __shfl_xor(s[r], 16);
    }

    // finalize: compile-time indices only (no scratch)
    float ft[4];
    #pragma unroll
    for (int r = 0; r < 4; ++r)
        ft[r] = -eps * LN2 * (m[r] + __log2f(s[r]) + Kc[r]);

    if (round < 17) {
        #pragma unroll
        for (int r = 0; r < 4; ++r) {
            if (l == r) {
                const int i = i0 + r;
                obuf[i] = (round == 0) ? ft[r] : 0.5f * (oldb[i] + ft[r]);
            }
        }
    } else {
        // fused reduction: sum of all f_fin and g_fin entries, scaled by 1/N
        float v = 0.0f;
        if (l == 0) v = (ft[0] + ft[1]) + (ft[2] + ft[3]);
        #pragma unroll
        for (int o = 1; o < 64; o <<= 1) v += __shfl_xor(v, o);
        const int w = t >> 6;
        if ((t & 63) == 0) wsum[w] = v;
        __syncthreads();
        if (t == 0) {
            float tot = (wsum[0] + wsum[1]) + (wsum[2] + wsum[3]);
            atomicAdd(out, tot * (1.0f / NP));
        }
    }
}

extern "C" void kernel_launch(void* const* d_in, const int* in_sizes, int n_in,
                              void* d_out, int out_size, void* d_ws, size_t ws_size,
                              hipStream_t stream) {
    const float* x = (const float*)d_in[0];
    const float* y = (const float*)d_in[1];
    float* out = (float*)d_out;
    float* ws  = (float*)d_ws;

    hipMemsetAsync(out, 0, sizeof(float), stream);
    hipLaunchKernelGGL(sk_setup, dim3(BN), dim3(256), 0, stream, x, y, ws);
    for (int r = 0; r < 18; ++r) {
        hipLaunchKernelGGL(sk_round, dim3(1536), dim3(256), 0, stream,
                           x, y, ws, out, r);
    }
}

// Round 9
// 442.408 us; speedup vs baseline: 7.0449x; 7.0449x over previous
//
#include <hip/hip_runtime.h>
#include <math.h>

// Sinkhorn loss, B=16 batches of N=1536 1D points, fp32.
// 18 softmin rounds, one kernel launch each (cooperative launch rejected by
// this harness -- R3/R7 failed with d_out untouched).
// R8: 1536 blocks + 4-deep LDS load batches; BUT __launch_bounds__(256,6)
//     clamped VGPR to 40 -> scratch spills -> 545 MB HBM traffic/round,
//     183 us/round (memory-bound on spill traffic, VALUBusy 6.7%).
// R9: drop the min-waves constraint (plain __launch_bounds__(256)). Kernel
//     needs ~70 VGPR -> ~7 waves/SIMD naturally, zero spill.
//
// ws layout (floats): eps0[16] | F0[B*N] | F1[B*N] | G0[B*N] | G1[B*N]

static constexpr int   BN    = 16;
static constexpr int   NP    = 1536;
static constexpr float BLUR2 = 0.0025f;                 // blur^2
static constexpr float L2E   = 1.4426950408889634f;     // log2(e)
static constexpr float LN2   = 0.6931471805599453f;     // ln(2)
static constexpr float HLOG  = -7.33693691f;            // -log(1536)

#if defined(__has_builtin)
#if __has_builtin(__builtin_amdgcn_exp2f)
#define EXP2F(x) __builtin_amdgcn_exp2f(x)
#else
#define EXP2F(x) exp2f(x)
#endif
#else
#define EXP2F(x) exp2f(x)
#endif

__global__ __launch_bounds__(256) void sk_setup(const float* __restrict__ x,
                                                const float* __restrict__ y,
                                                float* __restrict__ eps0) {
    const int b = blockIdx.x;
    const int t = threadIdx.x;
    float mn = INFINITY, mx = -INFINITY;
    for (int j = t; j < NP; j += 256) {
        float xv = x[b * NP + j], yv = y[b * NP + j];
        mn = fminf(mn, fminf(xv, yv));
        mx = fmaxf(mx, fmaxf(xv, yv));
    }
    for (int o = 1; o < 64; o <<= 1) {
        mn = fminf(mn, __shfl_xor(mn, o));
        mx = fmaxf(mx, __shfl_xor(mx, o));
    }
    __shared__ float smn[4], smx[4];
    const int w = t >> 6;
    if ((t & 63) == 0) { smn[w] = mn; smx[w] = mx; }
    __syncthreads();
    if (t == 0) {
        mn = fminf(fminf(smn[0], smn[1]), fminf(smn[2], smn[3]));
        mx = fmaxf(fmaxf(smx[0], smx[1]), fmaxf(smx[2], smx[3]));
        float d = mx - mn;
        eps0[b] = d * d;
    }
}

// grid = 1536 blocks: batch (16) x {dir f: 48, dir g: 48} row-blocks of 32.
// Block = 8 groups x 32 lanes; group owns 4 rows, lanes split the columns.
__global__ __launch_bounds__(256) void sk_round(const float* __restrict__ x,
                                                const float* __restrict__ y,
                                                float* __restrict__ ws,
                                                float* __restrict__ out,
                                                int round) {
    __shared__ __align__(16) float2 cu[NP];   // (col_coord_j, U_j) ; 12 KB
    __shared__ float wsum[4];

    const int blk    = blockIdx.x;       // 0..1535
    const int batch  = blk / 96;
    const int rb     = blk % 96;
    const int dir    = (rb < 48) ? 0 : 1;
    const int rowblk = rb - dir * 48;    // 0..47

    float* F0 = ws + 16;
    float* F1 = F0 + BN * NP;
    float* G0 = F1 + BN * NP;
    float* G1 = G0 + BN * NP;
    const int ri = (round + 1) & 1;      // read parity
    const int wi = round & 1;            // write parity
    float* Fr = ri ? F1 : F0;  float* Fw = wi ? F1 : F0;
    float* Gr = ri ? G1 : G0;  float* Gw = wi ? G1 : G0;

    const float* colc; const float* rowc; const float* hsrc;
    float* obuf; const float* oldb;
    if (dir == 0) { // ft rows: rows over x_i, cols over y_j, h from g
        colc = y + batch * NP; rowc = x + batch * NP;
        hsrc = Gr + batch * NP; obuf = Fw + batch * NP; oldb = Fr + batch * NP;
    } else {        // gt rows: rows over y_i, cols over x_j, h from f
        colc = x + batch * NP; rowc = y + batch * NP;
        hsrc = Fr + batch * NP; obuf = Gw + batch * NP; oldb = Gr + batch * NP;
    }

    // eps_k = max(blur^2, eps0 * 0.25^max(k-1,0)); round 1..16 = step k-1
    const float e0 = ws[batch];
    float eps;
    if (round == 0)       eps = fmaxf(BLUR2, e0);
    else if (round >= 17) eps = BLUR2;
    else {
        int mk = round - 2; if (mk < 0) mk = 0;
        eps = fmaxf(BLUR2, e0 / (float)(1u << (2 * mk)));   // exact pow2 scale
    }
    const float ieps = 1.0f / eps;
    const float cL   = 0.5f * ieps * L2E;

    // Stage column table: U_j = L2E*h_j - cL*c_j^2, h_j = HLOG + g_j/eps
    const int t = threadIdx.x;
    for (int j = t; j < NP; j += 256) {
        float cj = colc[j];
        float hj = (round == 0) ? HLOG : fmaf(hsrc[j], ieps, HLOG);
        cu[j] = make_float2(cj, fmaf(L2E, hj, -cL * cj * cj));
    }
    __syncthreads();

    const int l  = t & 31;       // lane within group: splits columns
    const int g  = t >> 5;       // group 0..7: owns 4 rows
    const int i0 = rowblk * 32 + g * 4;

    float S[4], Kc[4];
    #pragma unroll
    for (int r = 0; r < 4; ++r) {
        float xi = rowc[i0 + r];
        S[r]  = 2.0f * cL * xi;          // exponent = U_j + S*col_j + Kc
        Kc[r] = -cL * xi * xi;
    }

    const float4* p = (const float4*)cu;   // 768 entries, 2 cols each
    // 24 strided iterations per lane, processed as 6 batches of 4 loads.

    // pass 1: max
    float m[4];
    #pragma unroll
    for (int r = 0; r < 4; ++r) m[r] = -INFINITY;
    #pragma unroll
    for (int qb = 0; qb < 6; ++qb) {
        const int q0 = l + qb * 128;               // qb*4 strides of 32
        float4 a0 = p[q0];
        float4 a1 = p[q0 + 32];
        float4 a2 = p[q0 + 64];
        float4 a3 = p[q0 + 96];
        #pragma unroll
        for (int r = 0; r < 4; ++r) {
            m[r] = fmaxf(fmaxf(fmaf(S[r], a0.x, a0.y), fmaf(S[r], a0.z, a0.w)), m[r]);
            m[r] = fmaxf(fmaxf(fmaf(S[r], a1.x, a1.y), fmaf(S[r], a1.z, a1.w)), m[r]);
            m[r] = fmaxf(fmaxf(fmaf(S[r], a2.x, a2.y), fmaf(S[r], a2.z, a2.w)), m[r]);
            m[r] = fmaxf(fmaxf(fmaf(S[r], a3.x, a3.y), fmaf(S[r], a3.z, a3.w)), m[r]);
        }
    }
    #pragma unroll
    for (int r = 0; r < 4; ++r) {
        m[r] = fmaxf(m[r], __shfl_xor(m[r], 1));
        m[r] = fmaxf(m[r], __shfl_xor(m[r], 2));
        m[r] = fmaxf(m[r], __shfl_xor(m[r], 4));
        m[r] = fmaxf(m[r], __shfl_xor(m[r], 8));
        m[r] = fmaxf(m[r], __shfl_xor(m[r], 16));
    }

    // pass 2: sum of 2^(v-m)
    float s[4];
    #pragma unroll
    for (int r = 0; r < 4; ++r) s[r] = 0.0f;
    #pragma unroll
    for (int qb = 0; qb < 6; ++qb) {
        const int q0 = l + qb * 128;
        float4 a0 = p[q0];
        float4 a1 = p[q0 + 32];
        float4 a2 = p[q0 + 64];
        float4 a3 = p[q0 + 96];
        #pragma unroll
        for (int r = 0; r < 4; ++r) {
            s[r] += EXP2F(fmaf(S[r], a0.x, a0.y) - m[r]);
            s[r] += EXP2F(fmaf(S[r], a0.z, a0.w) - m[r]);
            s[r] += EXP2F(fmaf(S[r], a1.x, a1.y) - m[r]);
            s[r] += EXP2F(fmaf(S[r], a1.z, a1.w) - m[r]);
            s[r] += EXP2F(fmaf(S[r], a2.x, a2.y) - m[r]);
            s[r] += EXP2F(fmaf(S[r], a2.z, a2.w) - m[r]);
            s[r] += EXP2F(fmaf(S[r], a3.x, a3.y) - m[r]);
            s[r] += EXP2F(fmaf(S[r], a3.z, a3.w) - m[r]);
        }
    }
    #pragma unroll
    for (int r = 0; r < 4; ++r) {
        s[r] += __shfl_xor(s[r], 1);
        s[r] += __shfl_xor(s[r], 2);
        s[r] += __shfl_xor(s[r], 4);
        s[r] += __shfl_xor(s[r], 8);
        s[r] += __shfl_xor(s[r], 16);
    }

    // finalize: compile-time indices only (no scratch)
    float ft[4];
    #pragma unroll
    for (int r = 0; r < 4; ++r)
        ft[r] = -eps * LN2 * (m[r] + __log2f(s[r]) + Kc[r]);

    if (round < 17) {
        #pragma unroll
        for (int r = 0; r < 4; ++r) {
            if (l == r) {
                const int i = i0 + r;
                obuf[i] = (round == 0) ? ft[r] : 0.5f * (oldb[i] + ft[r]);
            }
        }
    } else {
        // fused reduction: sum of all f_fin and g_fin entries, scaled by 1/N
        float v = 0.0f;
        if (l == 0) v = (ft[0] + ft[1]) + (ft[2] + ft[3]);
        #pragma unroll
        for (int o = 1; o < 64; o <<= 1) v += __shfl_xor(v, o);
        const int w = t >> 6;
        if ((t & 63) == 0) wsum[w] = v;
        __syncthreads();
        if (t == 0) {
            float tot = (wsum[0] + wsum[1]) + (wsum[2] + wsum[3]);
            atomicAdd(out, tot * (1.0f / NP));
        }
    }
}

extern "C" void kernel_launch(void* const* d_in, const int* in_sizes, int n_in,
                              void* d_out, int out_size, void* d_ws, size_t ws_size,
                              hipStream_t stream) {
    const float* x = (const float*)d_in[0];
    const float* y = (const float*)d_in[1];
    float* out = (float*)d_out;
    float* ws  = (float*)d_ws;

    hipMemsetAsync(out, 0, sizeof(float), stream);
    hipLaunchKernelGGL(sk_setup, dim3(BN), dim3(256), 0, stream, x, y, ws);
    for (int r = 0; r < 18; ++r) {
        hipLaunchKernelGGL(sk_round, dim3(1536), dim3(256), 0, stream,
                           x, y, ws, out, r);
    }
}